// Round 4
// baseline (106.565 us; speedup 1.0000x reference)
//
#include <hip/hip_runtime.h>

#define N 8192
#define EPS 1e-5f

#define TR 64          // rows per tile
#define TC 256         // cols per tile
#define NBJ 32         // N/TC col-tiles
#define NBI 128        // N/TR row-tiles
#define RPW 16         // rows per wave (4 waves/block)
#define SEG_W 4096     // worst-case edges per wave segment (RPW*TC) -> never overflows
#define NTILES 2112    // active upper-tri tiles
#define NSEG (NTILES * 4)
#define LLGRID 2048
#define DENSE_BLKS 1024  // k_ll blocks 0..1023: dense role (4 row-pairs each)

// ws layout (bytes):
//   accv  [0, 4096)        64 double slots, stride 8 doubles (1/cache line)
//   ovf   [4096]  done [4100]
//   deg   [4224, +32768)
//   cnt   [37 KB, +NSEG*4)
//   edges [..., +NSEG*SEG_W*4)   total ~132 MB
static const size_t OFF_ACC = 0;
static const size_t OFF_OVF = 4096;
static const size_t OFF_DONE = 4100;
static const size_t OFF_DEG = 4224;
static const size_t OFF_CNT = OFF_DEG + (size_t)N * 4;
static const size_t OFF_EDG = OFF_CNT + (size_t)NSEG * 4;
static const size_t WS_NEED = OFF_EDG + (size_t)NSEG * SEG_W * 4;

__device__ __forceinline__ unsigned mbcnt64(unsigned long long m) {
    return __builtin_amdgcn_mbcnt_hi((unsigned)(m >> 32),
           __builtin_amdgcn_mbcnt_lo((unsigned)m, 0u));
}

__global__ void k_init(float* __restrict__ deg, double* __restrict__ accv,
                       unsigned* __restrict__ ovf, unsigned* __restrict__ done,
                       const int segmode) {
    const int t = blockIdx.x * 256 + threadIdx.x;
    if (t < 512) accv[t] = 0.0;
    if (t == 513) *ovf = segmode ? 0u : 1u;
    if (t == 514) *done = 0u;
    if (t < N) deg[t] = 0.f;
}

// Pass 1: stream the upper triangle once. Row sums via popc of ballots
// (values exactly 0/1); edges stored DIRECTLY to the wave's private global
// segment via ballot-rank (exec-masked stores) -- no LDS buffer, no flush,
// no overflow possible (SEG_W == worst case). Next row prefetched before
// processing the current one so VMEM stays ahead of the branchy body.
__global__ __launch_bounds__(256) void k_pass1(const float* __restrict__ g,
        float* __restrict__ deg, unsigned* __restrict__ cnt,
        unsigned* __restrict__ edges, const int segmode) {
    const int bj = (int)blockIdx.x & (NBJ - 1);
    const int bi = (int)blockIdx.x >> 5;
    if (bi > 4 * bj + 3) return;                 // tile fully below diagonal
    const int r0 = bi * TR, c0 = bj * TC;
    const int wave = threadIdx.x >> 6, lane = threadIdx.x & 63;
    const int aid = 2 * bj * (bj + 1) + bi;      // compact active-tile index

    __shared__ float scol[TC];
    scol[threadIdx.x] = 0.f;
    __syncthreads();

    const int c = c0 + lane * 4;
    const int rbase = r0 + wave * RPW;
    unsigned wc = 0;
    unsigned* __restrict__ myseg = edges + ((size_t)aid * 4 + wave) * SEG_W;
    float ca0 = 0.f, ca1 = 0.f, ca2 = 0.f, ca3 = 0.f;
    const float* __restrict__ gp = g + (size_t)rbase * N + c;

#define EMIT(BB, PRED, OFFv) \
    if (BB) { const unsigned p_ = __popcll(BB); \
        if (segmode && (PRED)) myseg[wc + mbcnt64(BB)] = etag | (OFFv); \
        wc += p_; rsum += p_; }

    if (r0 + TR <= c0) {
        // strictly-above-diagonal tile: no triangle masks needed
        float4 v = *reinterpret_cast<const float4*>(gp);
        for (int k = 0; k < RPW; ++k) {
            float4 vn = v;
            if (k + 1 < RPW) vn = *reinterpret_cast<const float4*>(gp + (size_t)(k + 1) * N);
            const unsigned long long b0 = __ballot(v.x != 0.f);
            const unsigned long long b1 = __ballot(v.y != 0.f);
            const unsigned long long b2 = __ballot(v.z != 0.f);
            const unsigned long long b3 = __ballot(v.w != 0.f);
            if (b0 | b1 | b2 | b3) {
                const int gr = rbase + k;
                const unsigned etag = ((unsigned)gr << 16) | (unsigned)c;
                unsigned rsum = 0;
                ca0 += v.x; ca1 += v.y; ca2 += v.z; ca3 += v.w;
                EMIT(b0, v.x != 0.f, 0u)
                EMIT(b1, v.y != 0.f, 1u)
                EMIT(b2, v.z != 0.f, 2u)
                EMIT(b3, v.w != 0.f, 3u)
                if (lane == 0) atomicAdd(&deg[gr], (float)rsum);
            }
            v = vn;
        }
    } else {
        // diagonal-crossing tile: per-element triangle masks
        int nrows = c0 + TC - rbase;
        if (nrows > RPW) nrows = RPW;
        if (nrows > 0) {
            float4 v = *reinterpret_cast<const float4*>(gp);
            for (int k = 0; k < nrows; ++k) {
                float4 vn = v;
                if (k + 1 < nrows) vn = *reinterpret_cast<const float4*>(gp + (size_t)(k + 1) * N);
                const int gr = rbase + k;
                const bool a0 = (v.x != 0.f) && (c + 0 >= gr);
                const bool a1 = (v.y != 0.f) && (c + 1 >= gr);
                const bool a2 = (v.z != 0.f) && (c + 2 >= gr);
                const bool a3 = (v.w != 0.f) && (c + 3 >= gr);
                const unsigned long long b0 = __ballot(a0);
                const unsigned long long b1 = __ballot(a1);
                const unsigned long long b2 = __ballot(a2);
                const unsigned long long b3 = __ballot(a3);
                if (b0 | b1 | b2 | b3) {
                    const unsigned etag = ((unsigned)gr << 16) | (unsigned)c;
                    unsigned rsum = 0;
                    ca0 += (c + 0 > gr) ? v.x : 0.f;
                    ca1 += (c + 1 > gr) ? v.y : 0.f;
                    ca2 += (c + 2 > gr) ? v.z : 0.f;
                    ca3 += (c + 3 > gr) ? v.w : 0.f;
                    EMIT(b0, a0, 0u)
                    EMIT(b1, a1, 1u)
                    EMIT(b2, a2, 2u)
                    EMIT(b3, a3, 3u)
                    if (lane == 0) atomicAdd(&deg[gr], (float)rsum);
                }
                v = vn;
            }
        }
    }
#undef EMIT

    if (segmode && lane == 0) cnt[aid * 4 + wave] = wc;
    // column (strict-lower counterpart) sums: LDS-combine then one flush
    if (ca0 != 0.f) atomicAdd(&scol[lane * 4 + 0], ca0);
    if (ca1 != 0.f) atomicAdd(&scol[lane * 4 + 1], ca1);
    if (ca2 != 0.f) atomicAdd(&scol[lane * 4 + 2], ca2);
    if (ca3 != 0.f) atomicAdd(&scol[lane * 4 + 3], ca3);
    __syncthreads();
    const float sv = scol[threadIdx.x];
    if (sv != 0.f) atomicAdd(&deg[c0 + threadIdx.x], sv);
}

// Fused: dense S0 (pair-balanced, grid-strided) + edge corrections +
// (tiny-ws) fallback + in-kernel final reduction via done-counter.
__global__ __launch_bounds__(256) void k_ll(const float* __restrict__ g,
        const float* __restrict__ deg, const float* __restrict__ params,
        const unsigned* __restrict__ cnt, const unsigned* __restrict__ edges,
        const unsigned* __restrict__ ovf, double* __restrict__ accv,
        unsigned* __restrict__ done, float* __restrict__ out) {
    const int b = blockIdx.x;
    const unsigned o = *ovf;
    const float alpha = params[0], beta = params[1], sigma = params[2];
    double dlocal = 0.0;

    if (!o) {
        if (b < DENSE_BLKS) {
            #pragma unroll
            for (int q = 0; q < 4; ++q) {
                const int r1 = b + q * DENSE_BLKS;      // 0..4095
                const int r2 = N - 1 - r1;              // pair: N+1 iters total
                const float base1 = fmaf(alpha, deg[r1], sigma);
                const float base2 = fmaf(alpha, deg[r2], sigma);
                float local = 0.f;
                for (int j = r1 + (int)threadIdx.x; j < N; j += 256) {
                    const float s = fmaf(beta, deg[j], base1);
                    const float p = __fdividef(1.f, 1.f + __expf(s));
                    local += __logf(1.f - p + EPS);
                }
                for (int j = r2 + (int)threadIdx.x; j < N; j += 256) {
                    const float s = fmaf(beta, deg[j], base2);
                    const float p = __fdividef(1.f, 1.f + __expf(s));
                    local += __logf(1.f - p + EPS);
                }
                dlocal += (double)local;
            }
        } else {
            float local = 0.f;
            for (int s = b - DENSE_BLKS; s < NSEG; s += LLGRID - DENSE_BLKS) {
                const unsigned n = cnt[s];
                const unsigned* __restrict__ seg = edges + (size_t)s * SEG_W;
                for (unsigned t = threadIdx.x; t < n; t += 256) {
                    const unsigned e = seg[t];
                    const float di = deg[e >> 16];
                    const float dj = deg[e & 0xffffu];
                    const float sc = fmaf(alpha, di, fmaf(beta, dj, sigma));
                    const float p = __fdividef(1.f, 1.f + __expf(sc));
                    local += __logf(p + EPS) - __logf(1.f - p + EPS);
                }
            }
            dlocal = (double)local;
        }
    } else {
        // fallback (ws too small for edge segments): direct upper-tri scan
        for (int i = b; i < N; i += LLGRID) {
            const float base = fmaf(alpha, deg[i], sigma);
            float rl = 0.f;
            for (int j = i + (int)threadIdx.x; j < N; j += 256) {
                const float s = fmaf(beta, deg[j], base);
                const float p = __fdividef(1.f, 1.f + __expf(s));
                const float gv = g[(size_t)i * N + j];
                rl += (gv != 0.f) ? __logf(p + EPS) : __logf(1.f - p + EPS);
            }
            dlocal += (double)rl;
        }
    }

    #pragma unroll
    for (int off = 32; off; off >>= 1) dlocal += __shfl_xor(dlocal, off);
    __shared__ double wsum[4];
    __shared__ int slast;
    const int wv = threadIdx.x >> 6, ln = threadIdx.x & 63;
    if (ln == 0) wsum[wv] = dlocal;
    __syncthreads();
    if (threadIdx.x == 0) {
        const double t = (wsum[0] + wsum[1]) + (wsum[2] + wsum[3]);
        if (t != 0.0) atomicAdd(&accv[(b & 63) * 8], t);   // 64 spread slots
        __threadfence();
        const unsigned old = atomicAdd(done, 1u);
        slast = (old == (unsigned)(LLGRID - 1));
    }
    __syncthreads();
    if (slast && wv == 0) {
        __threadfence();
        double v = atomicAdd(&accv[ln * 8], 0.0);          // atomic read
        #pragma unroll
        for (int off = 32; off; off >>= 1) v += __shfl_xor(v, off);
        if (ln == 0) out[0] = (float)(-v);
    }
}

extern "C" void kernel_launch(void* const* d_in, const int* in_sizes, int n_in,
                              void* d_out, int out_size, void* d_ws, size_t ws_size,
                              hipStream_t stream) {
    const float* params = (const float*)d_in[0];   // [alpha, beta, sigma]
    const float* graph  = (const float*)d_in[1];   // [N, N] fp32 0/1
    float* out = (float*)d_out;

    char* ws = (char*)d_ws;
    double*   accv  = (double*)(ws + OFF_ACC);
    unsigned* ovf   = (unsigned*)(ws + OFF_OVF);
    unsigned* done  = (unsigned*)(ws + OFF_DONE);
    float*    deg   = (float*)(ws + OFF_DEG);
    unsigned* cnt   = (unsigned*)(ws + OFF_CNT);
    unsigned* edges = (unsigned*)(ws + OFF_EDG);
    const int segmode = (ws_size >= WS_NEED) ? 1 : 0;

    k_init<<<32, 256, 0, stream>>>(deg, accv, ovf, done, segmode);
    k_pass1<<<NBI * NBJ, 256, 0, stream>>>(graph, deg, cnt, edges, segmode);
    k_ll<<<LLGRID, 256, 0, stream>>>(graph, deg, params, cnt, edges, ovf, accv, done, out);
}

// Round 5
// 105.839 us; speedup vs baseline: 1.0069x; 1.0069x over previous
//
#include <hip/hip_runtime.h>

#define N 8192
#define EPS 1e-5f

#define TR 64          // rows per tile
#define TC 256         // cols per tile
#define NBJ 32         // N/TC col-tiles
#define NBI 128        // N/TR row-tiles
#define RPW 16         // rows per wave (4 waves/block)
#define NBLK (NBI * NBJ)   // 4096 dispatched blocks (2112 touch the triangle)

// ws layout (bytes):
//   deg     [0, 32768)            float[N]
//   partial [32768, 65536)        double[NBLK]  (one slot per block, no atomics)
//   bitmap  [65536, +NBLK*4*RPW*32) = 8.4 MB    (4x u64 ballot masks per wave-row)
static const size_t OFF_DEG  = 0;
static const size_t OFF_PART = 32768;
static const size_t OFF_BM   = 65536;
static const size_t WS_NEED  = OFF_BM + (size_t)NBLK * 4 * RPW * 32;

struct BM4 { unsigned long long b0, b1, b2, b3; };

// ---------------------------------------------------------------------------
// Pass 1: stream the upper triangle once. Row sums via popc of ballots
// (graph values are exactly 0/1); column (transposed-lower) sums via
// per-lane registers -> LDS -> one distributed atomic per column. Lane 0
// stores the 4 ballot masks per row: a 32x-compressed triangle bitmap that
// pass 2 reads instead of the graph.
// ---------------------------------------------------------------------------
__global__ __launch_bounds__(256) void k_deg(const float* __restrict__ g,
        float* __restrict__ deg, BM4* __restrict__ bm, const int bmmode) {
    const int bj = (int)blockIdx.x & (NBJ - 1);
    const int bi = (int)blockIdx.x >> 5;
    if (bi > 4 * bj + 3) return;                 // tile fully below diagonal
    const int r0 = bi * TR, c0 = bj * TC;
    const int wave = threadIdx.x >> 6, lane = threadIdx.x & 63;

    __shared__ float scol[TC];
    scol[threadIdx.x] = 0.f;
    __syncthreads();

    const int c = c0 + lane * 4;
    const int rbase = r0 + wave * RPW;
    const float* __restrict__ gp = g + (size_t)rbase * N + c;
    BM4* __restrict__ mybm = bm + ((size_t)blockIdx.x * 4 + wave) * RPW;
    float ca0 = 0.f, ca1 = 0.f, ca2 = 0.f, ca3 = 0.f;

    if (r0 + TR <= c0) {
        // strictly-above-diagonal tile: every element is in the triangle
        #pragma unroll 4
        for (int k = 0; k < RPW; ++k) {
            const float4 v = *reinterpret_cast<const float4*>(gp + (size_t)k * N);
            const unsigned long long b0 = __ballot(v.x != 0.f);
            const unsigned long long b1 = __ballot(v.y != 0.f);
            const unsigned long long b2 = __ballot(v.z != 0.f);
            const unsigned long long b3 = __ballot(v.w != 0.f);
            ca0 += v.x; ca1 += v.y; ca2 += v.z; ca3 += v.w;
            if (lane == 0) {
                if (bmmode) { BM4 m; m.b0 = b0; m.b1 = b1; m.b2 = b2; m.b3 = b3; mybm[k] = m; }
                const unsigned rsum = __popcll(b0) + __popcll(b1) + __popcll(b2) + __popcll(b3);
                if (rsum) atomicAdd(&deg[rbase + k], (float)rsum);
            }
        }
    } else {
        // diagonal-crossing tile: per-element triangle masks (all 16 rows of
        // every wave still intersect the triangle for active tiles)
        for (int k = 0; k < RPW; ++k) {
            const int gr = rbase + k;
            const float4 v = *reinterpret_cast<const float4*>(gp + (size_t)k * N);
            const bool a0 = (v.x != 0.f) && (c + 0 >= gr);
            const bool a1 = (v.y != 0.f) && (c + 1 >= gr);
            const bool a2 = (v.z != 0.f) && (c + 2 >= gr);
            const bool a3 = (v.w != 0.f) && (c + 3 >= gr);
            const unsigned long long b0 = __ballot(a0);
            const unsigned long long b1 = __ballot(a1);
            const unsigned long long b2 = __ballot(a2);
            const unsigned long long b3 = __ballot(a3);
            ca0 += (c + 0 > gr) ? v.x : 0.f;
            ca1 += (c + 1 > gr) ? v.y : 0.f;
            ca2 += (c + 2 > gr) ? v.z : 0.f;
            ca3 += (c + 3 > gr) ? v.w : 0.f;
            if (lane == 0) {
                if (bmmode) { BM4 m; m.b0 = b0; m.b1 = b1; m.b2 = b2; m.b3 = b3; mybm[k] = m; }
                const unsigned rsum = __popcll(b0) + __popcll(b1) + __popcll(b2) + __popcll(b3);
                if (rsum) atomicAdd(&deg[gr], (float)rsum);
            }
        }
    }

    if (ca0 != 0.f) atomicAdd(&scol[lane * 4 + 0], ca0);
    if (ca1 != 0.f) atomicAdd(&scol[lane * 4 + 1], ca1);
    if (ca2 != 0.f) atomicAdd(&scol[lane * 4 + 2], ca2);
    if (ca3 != 0.f) atomicAdd(&scol[lane * 4 + 3], ca3);
    __syncthreads();
    const float sv = scol[threadIdx.x];
    if (sv != 0.f) atomicAdd(&deg[c0 + threadIdx.x], sv);
}

// ---------------------------------------------------------------------------
// Pass 2: full likelihood per triangle element, reading only the 4.2 MB
// bitmap (USEBM=1) or the graph directly (USEBM=0 tiny-ws fallback).
//   s = alpha*deg_i + beta*deg_j + sigma;  p = 1/(1+e^s);  1-p = e^s * p
//   contrib = log( edge ? p+eps : fma(e, p, eps) )
// Per-block partial -> private slot (no atomics anywhere).
// ---------------------------------------------------------------------------
template <int USEBM>
__global__ __launch_bounds__(256) void k_ll(const float* __restrict__ g,
        const float* __restrict__ deg, const float* __restrict__ params,
        const BM4* __restrict__ bm, double* __restrict__ partial) {
    const int bj = (int)blockIdx.x & (NBJ - 1);
    const int bi = (int)blockIdx.x >> 5;
    double dacc = 0.0;

    if (bi <= 4 * bj + 3) {
        const int r0 = bi * TR, c0 = bj * TC;
        const int wave = threadIdx.x >> 6, lane = threadIdx.x & 63;
        const int c = c0 + lane * 4;
        const int rbase = r0 + wave * RPW;
        const BM4* __restrict__ mybm = bm + ((size_t)blockIdx.x * 4 + wave) * RPW;
        const float* __restrict__ gp = g + (size_t)rbase * N + c;
        const float alpha = params[0], beta = params[1], sigma = params[2];
        const float4 dv = *reinterpret_cast<const float4*>(deg + c);
        const float bs0 = beta * dv.x, bs1 = beta * dv.y;
        const float bs2 = beta * dv.z, bs3 = beta * dv.w;
        float acc = 0.f;

#define ELEM(BS, EDGE) { \
        const float e_ = __expf(basei + (BS)); \
        const float p_ = __fdividef(1.f, 1.f + e_); \
        const float arg_ = (EDGE) ? (p_ + EPS) : fmaf(e_, p_, EPS); \
        lv = __logf(arg_); }

        if (r0 + TR <= c0) {
            #pragma unroll 4
            for (int k = 0; k < RPW; ++k) {
                BM4 m; float4 v;
                if (USEBM) m = mybm[k];
                else       v = *reinterpret_cast<const float4*>(gp + (size_t)k * N);
                const float basei = fmaf(alpha, deg[rbase + k], sigma);
                float lv;
                ELEM(bs0, USEBM ? (bool)((m.b0 >> lane) & 1ull) : (v.x != 0.f)); acc += lv;
                ELEM(bs1, USEBM ? (bool)((m.b1 >> lane) & 1ull) : (v.y != 0.f)); acc += lv;
                ELEM(bs2, USEBM ? (bool)((m.b2 >> lane) & 1ull) : (v.z != 0.f)); acc += lv;
                ELEM(bs3, USEBM ? (bool)((m.b3 >> lane) & 1ull) : (v.w != 0.f)); acc += lv;
            }
        } else {
            for (int k = 0; k < RPW; ++k) {
                const int gr = rbase + k;
                BM4 m; float4 v;
                if (USEBM) m = mybm[k];
                else       v = *reinterpret_cast<const float4*>(gp + (size_t)k * N);
                const float basei = fmaf(alpha, deg[gr], sigma);
                float lv;
                // bitmap bits already include the triangle mask; the dense
                // term still needs the explicit c>=gr gate
                ELEM(bs0, USEBM ? (bool)((m.b0 >> lane) & 1ull) : (v.x != 0.f && c + 0 >= gr));
                acc += (c + 0 >= gr) ? lv : 0.f;
                ELEM(bs1, USEBM ? (bool)((m.b1 >> lane) & 1ull) : (v.y != 0.f && c + 1 >= gr));
                acc += (c + 1 >= gr) ? lv : 0.f;
                ELEM(bs2, USEBM ? (bool)((m.b2 >> lane) & 1ull) : (v.z != 0.f && c + 2 >= gr));
                acc += (c + 2 >= gr) ? lv : 0.f;
                ELEM(bs3, USEBM ? (bool)((m.b3 >> lane) & 1ull) : (v.w != 0.f && c + 3 >= gr));
                acc += (c + 3 >= gr) ? lv : 0.f;
            }
        }
#undef ELEM
        dacc = (double)acc;
    }

    #pragma unroll
    for (int off = 32; off; off >>= 1) dacc += __shfl_xor(dacc, off);
    __shared__ double wsum[4];
    const int wv = threadIdx.x >> 6, ln = threadIdx.x & 63;
    if (ln == 0) wsum[wv] = dacc;
    __syncthreads();
    if (threadIdx.x == 0)
        partial[blockIdx.x] = (wsum[0] + wsum[1]) + (wsum[2] + wsum[3]);
}

__global__ void k_final(const double* __restrict__ partial, float* __restrict__ out) {
    double s = 0.0;
    for (int i = threadIdx.x; i < NBLK; i += 256) s += partial[i];
    #pragma unroll
    for (int off = 32; off; off >>= 1) s += __shfl_xor(s, off);
    __shared__ double wsum[4];
    if ((threadIdx.x & 63) == 0) wsum[threadIdx.x >> 6] = s;
    __syncthreads();
    if (threadIdx.x == 0)
        out[0] = (float)(-((wsum[0] + wsum[1]) + (wsum[2] + wsum[3])));
}

extern "C" void kernel_launch(void* const* d_in, const int* in_sizes, int n_in,
                              void* d_out, int out_size, void* d_ws, size_t ws_size,
                              hipStream_t stream) {
    const float* params = (const float*)d_in[0];   // [alpha, beta, sigma]
    const float* graph  = (const float*)d_in[1];   // [N, N] fp32 0/1
    float* out = (float*)d_out;

    char* ws = (char*)d_ws;
    float*  deg     = (float*)(ws + OFF_DEG);
    double* partial = (double*)(ws + OFF_PART);
    BM4*    bm      = (BM4*)(ws + OFF_BM);
    const int bmmode = (ws_size >= WS_NEED) ? 1 : 0;

    hipMemsetAsync(deg, 0, (size_t)N * sizeof(float), stream);
    k_deg<<<NBLK, 256, 0, stream>>>(graph, deg, bm, bmmode);
    if (bmmode)
        k_ll<1><<<NBLK, 256, 0, stream>>>(graph, deg, params, bm, partial);
    else
        k_ll<0><<<NBLK, 256, 0, stream>>>(graph, deg, params, bm, partial);
    k_final<<<1, 256, 0, stream>>>(partial, out);
}

// Round 6
// 75.485 us; speedup vs baseline: 1.4117x; 1.4021x over previous
//
#include <hip/hip_runtime.h>

#define N 8192
#define EPS 1e-5f

#define TR 64          // rows per tile
#define TC 256         // cols per tile
#define NBJ 32         // N/TC col-tiles
#define NBI 128        // N/TR row-tiles
#define RPW 16         // rows per wave (4 waves/block)
#define CAPW 512       // per-wave LDS edge buffer entries (flush at >256; max 256/row)
#define SEG_W 4096     // worst-case edges per wave segment (RPW*TC) -> never overflows
#define NTILES 2112    // active upper-tri tiles
#define NSEG (NTILES * 4)
#define NDENSE 4096    // dense pair-blocks
#define NFB 1024       // fallback blocks (tiny-ws path only)

// ws layout (bytes):
//   accv [0,4096)  64 double slots, stride 8 doubles (1/cache line)
//   ovf  [4096]
//   deg  [4224, +32768)
//   cnt  [~37KB, +NSEG*4)
//   edges[..., +NSEG*SEG_W*4)  total ~138 MB
static const size_t OFF_ACC = 0;
static const size_t OFF_OVF = 4096;
static const size_t OFF_DEG = 4224;
static const size_t OFF_CNT = OFF_DEG + (size_t)N * 4;
static const size_t OFF_EDG = OFF_CNT + (size_t)NSEG * 4;
static const size_t WS_NEED = OFF_EDG + (size_t)NSEG * SEG_W * 4;

__device__ __forceinline__ unsigned mbcnt64(unsigned long long m) {
    return __builtin_amdgcn_mbcnt_hi((unsigned)(m >> 32),
           __builtin_amdgcn_mbcnt_lo((unsigned)m, 0u));
}

__global__ void k_init(float* __restrict__ deg, double* __restrict__ accv,
                       unsigned* __restrict__ ovf, const int segmode) {
    const int t = blockIdx.x * 256 + threadIdx.x;
    if (t < 512) accv[t] = 0.0;
    if (t == 513) *ovf = segmode ? 0u : 1u;
    if (t < N) deg[t] = 0.f;
}

// Pass 1: stream the upper triangle once. Row sums via popc of ballots
// (graph values are exactly 0/1). Edge compaction: ballot-rank into a
// per-wave LDS buffer with the running count in a wave-uniform REGISTER
// (no LDS atomics, no LDS read in the flush check), flushed coalesced to
// a deterministic per-(tile,wave) global segment sized for the worst case.
__global__ __launch_bounds__(256) void k_pass1(const float* __restrict__ g,
        float* __restrict__ deg, unsigned* __restrict__ cnt,
        unsigned* __restrict__ edges, const int segmode) {
    const int bj = (int)blockIdx.x & (NBJ - 1);
    const int bi = (int)blockIdx.x >> 5;
    if (bi > 4 * bj + 3) return;                 // tile fully below diagonal
    const int r0 = bi * TR, c0 = bj * TC;
    const int wave = threadIdx.x >> 6, lane = threadIdx.x & 63;
    const int aid = 2 * bj * (bj + 1) + bi;      // compact active-tile index

    __shared__ float    scol[TC];
    __shared__ unsigned buf[4][CAPW];
    scol[threadIdx.x] = 0.f;
    __syncthreads();

    const int c = c0 + lane * 4;
    const int rbase = r0 + wave * RPW;
    const float* __restrict__ gp = g + (size_t)rbase * N + c;
    unsigned* __restrict__ myseg = edges + ((size_t)aid * 4 + wave) * SEG_W;
    unsigned wc = 0, wflushed = 0;               // wave-uniform registers
    float ca0 = 0.f, ca1 = 0.f, ca2 = 0.f, ca3 = 0.f;

#define EMIT(BB, PRED, OFFv) \
    if (BB) { if (segmode && (PRED)) buf[wave][wc + mbcnt64(BB)] = etag | (OFFv); \
        const unsigned p_ = __popcll(BB); wc += p_; rsum += p_; }

#define FLUSHCHK \
    if (segmode && wc > (unsigned)(CAPW - 256)) { \
        for (unsigned t_ = lane; t_ < wc; t_ += 64) myseg[wflushed + t_] = buf[wave][t_]; \
        wflushed += wc; wc = 0; }

    if (r0 + TR <= c0) {
        // strictly-above-diagonal tile: every element is in the triangle
        #pragma unroll 4
        for (int k = 0; k < RPW; ++k) {
            const float4 v = *reinterpret_cast<const float4*>(gp + (size_t)k * N);
            FLUSHCHK
            ca0 += v.x; ca1 += v.y; ca2 += v.z; ca3 += v.w;
            const unsigned long long b0 = __ballot(v.x != 0.f);
            const unsigned long long b1 = __ballot(v.y != 0.f);
            const unsigned long long b2 = __ballot(v.z != 0.f);
            const unsigned long long b3 = __ballot(v.w != 0.f);
            if (b0 | b1 | b2 | b3) {
                const int gr = rbase + k;
                const unsigned etag = ((unsigned)gr << 16) | (unsigned)c;
                unsigned rsum = 0;
                EMIT(b0, v.x != 0.f, 0u)
                EMIT(b1, v.y != 0.f, 1u)
                EMIT(b2, v.z != 0.f, 2u)
                EMIT(b3, v.w != 0.f, 3u)
                if (lane == 0) atomicAdd(&deg[gr], (float)rsum);
            }
        }
    } else {
        // diagonal-crossing tile: per-element triangle masks (all 16 rows of
        // every active wave intersect the tile's column range by construction)
        for (int k = 0; k < RPW; ++k) {
            const int gr = rbase + k;
            const float4 v = *reinterpret_cast<const float4*>(gp + (size_t)k * N);
            FLUSHCHK
            const bool a0 = (v.x != 0.f) && (c + 0 >= gr);
            const bool a1 = (v.y != 0.f) && (c + 1 >= gr);
            const bool a2 = (v.z != 0.f) && (c + 2 >= gr);
            const bool a3 = (v.w != 0.f) && (c + 3 >= gr);
            ca0 += (c + 0 > gr) ? v.x : 0.f;
            ca1 += (c + 1 > gr) ? v.y : 0.f;
            ca2 += (c + 2 > gr) ? v.z : 0.f;
            ca3 += (c + 3 > gr) ? v.w : 0.f;
            const unsigned long long b0 = __ballot(a0);
            const unsigned long long b1 = __ballot(a1);
            const unsigned long long b2 = __ballot(a2);
            const unsigned long long b3 = __ballot(a3);
            if (b0 | b1 | b2 | b3) {
                const unsigned etag = ((unsigned)gr << 16) | (unsigned)c;
                unsigned rsum = 0;
                EMIT(b0, a0, 0u)
                EMIT(b1, a1, 1u)
                EMIT(b2, a2, 2u)
                EMIT(b3, a3, 3u)
                if (lane == 0) atomicAdd(&deg[gr], (float)rsum);
            }
        }
    }
#undef EMIT
#undef FLUSHCHK

    if (segmode) {
        for (unsigned t = lane; t < wc; t += 64) myseg[wflushed + t] = buf[wave][t];
        if (lane == 0) cnt[aid * 4 + wave] = wflushed + wc;
    }
    // column (strict-lower counterpart) sums: LDS-combine then one flush
    if (ca0 != 0.f) atomicAdd(&scol[lane * 4 + 0], ca0);
    if (ca1 != 0.f) atomicAdd(&scol[lane * 4 + 1], ca1);
    if (ca2 != 0.f) atomicAdd(&scol[lane * 4 + 2], ca2);
    if (ca3 != 0.f) atomicAdd(&scol[lane * 4 + 3], ca3);
    __syncthreads();
    const float sv = scol[threadIdx.x];
    if (sv != 0.f) atomicAdd(&deg[c0 + threadIdx.x], sv);
}

// Dense S0 (pair-balanced) + edge corrections + (tiny-ws) fallback.
__global__ __launch_bounds__(256) void k_ll(const float* __restrict__ g,
        const float* __restrict__ deg, const float* __restrict__ params,
        const unsigned* __restrict__ cnt, const unsigned* __restrict__ edges,
        const unsigned* __restrict__ ovf, double* __restrict__ accv) {
    const int b = blockIdx.x;
    const unsigned o = *ovf;
    const float alpha = params[0], beta = params[1], sigma = params[2];
    double dlocal = 0.0;

    if (b < NDENSE) {
        if (o) return;
        const int r1 = b, r2 = N - 1 - b;        // pair rows: N+1 iters/block
        const float base1 = fmaf(alpha, deg[r1], sigma);
        const float base2 = fmaf(alpha, deg[r2], sigma);
        float local = 0.f;
        for (int j = r1 + (int)threadIdx.x; j < N; j += 256) {
            const float s = fmaf(beta, deg[j], base1);
            const float p = __fdividef(1.f, 1.f + __expf(s));
            local += __logf(1.f - p + EPS);
        }
        for (int j = r2 + (int)threadIdx.x; j < N; j += 256) {
            const float s = fmaf(beta, deg[j], base2);
            const float p = __fdividef(1.f, 1.f + __expf(s));
            local += __logf(1.f - p + EPS);
        }
        dlocal = (double)local;
    } else if (b < NDENSE + NTILES) {
        if (o) return;
        const int aid = b - NDENSE;
        float local = 0.f;
        for (int w = 0; w < 4; ++w) {
            const unsigned n = cnt[aid * 4 + w];
            const unsigned* __restrict__ seg = edges + ((size_t)aid * 4 + w) * SEG_W;
            for (unsigned t = threadIdx.x; t < n; t += 256) {
                const unsigned e = seg[t];
                const float di = deg[e >> 16];
                const float dj = deg[e & 0xffffu];
                const float s = fmaf(alpha, di, fmaf(beta, dj, sigma));
                const float p = __fdividef(1.f, 1.f + __expf(s));
                local += __logf(p + EPS) - __logf(1.f - p + EPS);
            }
        }
        dlocal = (double)local;
    } else {
        if (!o) return;                          // fallback only when ws tiny
        const int rb = b - NDENSE - NTILES;
        for (int q = 0; q < 8; ++q) {
            const int i = rb * 8 + q;
            const float base = fmaf(alpha, deg[i], sigma);
            float rl = 0.f;
            for (int j = i + (int)threadIdx.x; j < N; j += 256) {
                const float s = fmaf(beta, deg[j], base);
                const float p = __fdividef(1.f, 1.f + __expf(s));
                const float gv = g[(size_t)i * N + j];
                rl += (gv != 0.f) ? __logf(p + EPS) : __logf(1.f - p + EPS);
            }
            dlocal += (double)rl;
        }
    }

    #pragma unroll
    for (int off = 32; off; off >>= 1) dlocal += __shfl_xor(dlocal, off);
    __shared__ double wsum[4];
    const int wv = threadIdx.x >> 6, ln = threadIdx.x & 63;
    if (ln == 0) wsum[wv] = dlocal;
    __syncthreads();
    if (threadIdx.x == 0) {
        const double t = (wsum[0] + wsum[1]) + (wsum[2] + wsum[3]);
        if (t != 0.0) atomicAdd(&accv[(b & 63) * 8], t);   // 64 spread slots
    }
}

__global__ void k_final(const double* __restrict__ accv, float* __restrict__ out) {
    double v = accv[threadIdx.x * 8];
    #pragma unroll
    for (int off = 32; off; off >>= 1) v += __shfl_xor(v, off);
    if (threadIdx.x == 0) out[0] = (float)(-v);
}

extern "C" void kernel_launch(void* const* d_in, const int* in_sizes, int n_in,
                              void* d_out, int out_size, void* d_ws, size_t ws_size,
                              hipStream_t stream) {
    const float* params = (const float*)d_in[0];   // [alpha, beta, sigma]
    const float* graph  = (const float*)d_in[1];   // [N, N] fp32 0/1
    float* out = (float*)d_out;

    char* ws = (char*)d_ws;
    double*   accv  = (double*)(ws + OFF_ACC);
    unsigned* ovf   = (unsigned*)(ws + OFF_OVF);
    float*    deg   = (float*)(ws + OFF_DEG);
    unsigned* cnt   = (unsigned*)(ws + OFF_CNT);
    unsigned* edges = (unsigned*)(ws + OFF_EDG);
    const int segmode = (ws_size >= WS_NEED) ? 1 : 0;

    k_init<<<32, 256, 0, stream>>>(deg, accv, ovf, segmode);
    k_pass1<<<NBI * NBJ, 256, 0, stream>>>(graph, deg, cnt, edges, segmode);
    k_ll<<<NDENSE + NTILES + NFB, 256, 0, stream>>>(graph, deg, params, cnt, edges, ovf, accv);
    k_final<<<1, 64, 0, stream>>>(accv, out);
}